// Round 4
// baseline (452.413 us; speedup 1.0000x reference)
//
#include <hip/hip_runtime.h>
#include <math.h>

#define B_ 64
#define P_ 25
#define D_ 128
#define T_ 120
#define L_ 2
#define K_ 4
#define GT 2                  // t-slices per block; 2 row-waves each -> 4 waves/block
#define LN_EPS 1e-5f
#define HSTRF 132             // fp32 LDS row stride: 16B-aligned, %32==4 -> <=2-way banks

typedef __attribute__((ext_vector_type(8))) _Float16 half8;  // MFMA A/B frag
typedef __attribute__((ext_vector_type(4))) float f4v;       // MFMA accumulator

// Pre-swizzle W[l][k][n] (fp32) into per-lane fp16 B-fragments:
// wf[(((l*8+nt)*4+ks)*64+lane)*8 + j] = f16( W[l][ks*32+(lane>>4)*8+j][nt*16+(lane&15)] )
__global__ __launch_bounds__(256) void pack_w(const float* __restrict__ W,
                                              _Float16* __restrict__ wf) {
    int id = blockIdx.x * 256 + threadIdx.x;          // 0..4095
    int lane = id & 63, rest = id >> 6;
    int ks = rest & 3, nt = (rest >> 2) & 7, l = rest >> 5;
    int n  = nt * 16 + (lane & 15);
    int kb = ks * 32 + (lane >> 4) * 8;
    _Float16 v[8];
    for (int j = 0; j < 8; ++j)
        v[j] = (_Float16)W[((size_t)l * D_ + kb + j) * D_ + n];
    *reinterpret_cast<half8*>(wf + (size_t)id * 8) = *reinterpret_cast<half8*>(v);
}

// Round 1: 24 waves/CU but 8-wave barriers phase-locked them -> 197us.
// Round 2: fully independent waves but only 12/CU -> 197us.
// Round 3: ILP-via-arrays -> compiler pinned VGPR at 84 and spilled -> 237us.
// This round: 24 waves/CU in SMALL coupling groups. Block = (1 b, 2 t) x
// 2 row-waves = 4 waves, 26.9KB LDS -> 6 blocks/CU = 24 waves/CU, barriers
// couple only 4 waves, 6 independent blocks/CU drift out of phase. Row-split
// halves per-wave mix/VALU work; VGPR need ~70 fits the allocator's 85-reg
// sweet spot (launch_bounds(256,6) -> cap 85, matching LDS-allowed 6 wv/EU).
__global__ __launch_bounds__(256, 6) void gcn_mfma(
    const float* __restrict__ x,       // [B,P,D,T]
    const float* __restrict__ dist,    // [B,T,P,P]
    const _Float16* __restrict__ wf,   // packed fp16 W fragments
    const float* __restrict__ biases,  // [L,D]
    const float* __restrict__ gamma,   // [L,D]
    const float* __restrict__ beta,    // [L,D]
    float* __restrict__ out)           // [B,P,D,T]
{
    const int b = blockIdx.x, tg = blockIdx.y;
    const int t0 = tg * GT;
    const int tid = threadIdx.x;
    const int wave = tid >> 6, lane = tid & 63;

    __shared__ __align__(16) float h_lds[GT][P_][HSTRF];  // fp32 h (26.4 KB)
    __shared__ unsigned nbr32[GT][32];                    // packed 4x u8 nbr idx

    // ---- kNN: waves 0,1 handle t-slice = wave, one row per lane (lane<25).
    //      dist loads issued first; selection deferred below the x-load so
    //      HBM latency hides under staging. dr[] register-resident (literal
    //      indices only -> no scratch).
    float dr[P_];
    const bool doknn = (wave < GT) && (lane < P_);
    if (doknn) {
        const float* drow = dist + (((size_t)b * T_ + t0 + wave) * P_ + lane) * P_;
        #pragma unroll
        for (int q = 0; q < P_; ++q) {
            float v = drow[q];
            dr[q] = (q == lane) ? 1e30f : v;   // mask self, literal index
        }
    }

    // ---- load x -> h fp32 (float2 across the 2 t's: 8B-dense; 64B x-lines
    //      shared by 8 consecutive tg-blocks, all on the same XCD) ----
    {
        const float* xb = x + (size_t)b * P_ * D_ * T_ + t0;
        for (int i = tid; i < P_ * D_; i += 256) {
            int p = i >> 7, d = i & 127;
            float2 v = *reinterpret_cast<const float2*>(xb + (size_t)i * T_);
            h_lds[0][p][d] = v.x;
            h_lds[1][p][d] = v.y;
        }
    }

    // ---- kNN selection (row degree always K+1=5 -> adj = A/5) ----
    if (doknn) {
        unsigned chosen = 0, packed = 0;
        #pragma unroll
        for (int j = 0; j < K_; ++j) {
            float best = 1e29f; int bi = 0;
            #pragma unroll
            for (int q = 0; q < P_; ++q)   // strict < -> lowest index wins ties
                if (!((chosen >> q) & 1u) && dr[q] < best) { best = dr[q]; bi = q; }
            chosen |= 1u << bi;
            packed |= (unsigned)bi << (8 * j);
        }
        nbr32[wave][lane] = packed;
    }
    __syncthreads();   // h + nbr visible to all 4 waves

    const int t  = wave >> 1;          // t-slice owned by this wave
    const int rt = wave & 1;           // row-tile: rows rt*16 .. rt*16+15
    const int m = lane & 15, quad = lane >> 4;
    const int row = rt * 16 + m;
    const bool vR = (row < P_);
    const int  pr = vR ? row : 0;
    const float sc = vR ? 0.2f : 0.0f;  // zero out padded rows 25..31
    const float* hb = &h_lds[t][0][0];
    const unsigned nw = nbr32[t][pr];
    const int n0 = nw & 255, n1 = (nw >> 8) & 255, n2 = (nw >> 16) & 255, n3 = nw >> 24;

    for (int l = 0; l < L_; ++l) {
        f4v acc[8];
        #pragma unroll
        for (int nt = 0; nt < 8; ++nt)
            acc[nt] = (f4v){0.f, 0.f, 0.f, 0.f};
        const _Float16* wfl = wf + (size_t)l * 8 * 4 * 64 * 8;

        #pragma unroll
        for (int ks = 0; ks < 4; ++ks) {
            const int ko = ks * 32 + quad * 8;
            // ---- g = 0.2*(h[row] + sum of 4 nbr rows), exact fp32 ----
            float g[8];
            {
                const float* r  = hb + pr * HSTRF + ko;
                const float* p0 = hb + n0 * HSTRF + ko;
                const float* p1 = hb + n1 * HSTRF + ko;
                const float* p2 = hb + n2 * HSTRF + ko;
                const float* p3 = hb + n3 * HSTRF + ko;
                #pragma unroll
                for (int j = 0; j < 8; ++j)
                    g[j] = sc * (r[j] + p0[j] + p1[j] + p2[j] + p3[j]);
            }
            // ---- split-precision fp16 fragments: g ~= hi + lo (22-bit mantissa)
            half8 ahi, alo;
            #pragma unroll
            for (int j = 0; j < 8; ++j) {
                _Float16 h0 = (_Float16)g[j];
                ahi[j] = h0; alo[j] = (_Float16)(g[j] - (float)h0);
            }
            #pragma unroll
            for (int nt = 0; nt < 8; ++nt) {
                half8 bf = *reinterpret_cast<const half8*>(
                    wfl + (size_t)((nt * 4 + ks) * 64 + lane) * 8);  // coalesced, L2-hot
                acc[nt] = __builtin_amdgcn_mfma_f32_16x16x32_f16(ahi, bf, acc[nt], 0, 0, 0);
                acc[nt] = __builtin_amdgcn_mfma_f32_16x16x32_f16(alo, bf, acc[nt], 0, 0, 0);
            }
        }

        // Row-waves of a t share h_lds[t]: all mix reads must drain before
        // any epilogue residual write (WAR). Barrier couples only 4 waves.
        __syncthreads();

        // ---- epilogue in registers: bias + relu + LN + residual into h ----
        float bsv[8], gmv[8], btv[8];
        #pragma unroll
        for (int nt = 0; nt < 8; ++nt) {
            int c = l * D_ + nt * 16 + m;
            bsv[nt] = biases[c]; gmv[nt] = gamma[c]; btv[nt] = beta[c];
        }
        // C layout: col = nt*16 + (lane&15), row = rt*16 + quad*4 + r.
        // A row's 128 cols live in the 16 lanes of one quad -> xor 1,2,4,8.
        #pragma unroll
        for (int r = 0; r < 4; ++r) {
            const int mm = rt * 16 + quad * 4 + r;
            float z[8], s = 0.f, s2 = 0.f;
            #pragma unroll
            for (int nt = 0; nt < 8; ++nt) {
                float zz = fmaxf(acc[nt][r] + bsv[nt], 0.f);
                z[nt] = zz; s += zz; s2 += zz * zz;
            }
            #pragma unroll
            for (int o = 1; o < 16; o <<= 1) {   // reduce within quad (16 lanes)
                s  += __shfl_xor(s, o);
                s2 += __shfl_xor(s2, o);
            }
            if (mm < P_) {
                float mu  = s * (1.f / 128.f);
                float var = s2 * (1.f / 128.f) - mu * mu;
                float rs  = rsqrtf(var + LN_EPS);
                #pragma unroll
                for (int nt = 0; nt < 8; ++nt)
                    h_lds[t][mm][nt * 16 + m] += (z[nt] - mu) * rs * gmv[nt] + btv[nt];
            }
        }
        __syncthreads();   // h writes visible for next layer / store
    }

    // ---- store: out[b,p,d,t0..t0+1] as float2 ----
    {
        float* ob = out + (size_t)b * P_ * D_ * T_ + t0;
        for (int i = tid; i < P_ * D_; i += 256) {
            int p = i >> 7, d = i & 127;
            float2 v;
            v.x = h_lds[0][p][d];
            v.y = h_lds[1][p][d];
            *reinterpret_cast<float2*>(ob + (size_t)i * T_) = v;
        }
    }
}

extern "C" void kernel_launch(void* const* d_in, const int* in_sizes, int n_in,
                              void* d_out, int out_size, void* d_ws, size_t ws_size,
                              hipStream_t stream) {
    const float* x    = (const float*)d_in[0];
    const float* dist = (const float*)d_in[1];
    const float* w    = (const float*)d_in[2];
    const float* bias = (const float*)d_in[3];
    const float* gam  = (const float*)d_in[4];
    const float* bet  = (const float*)d_in[5];
    float* out = (float*)d_out;
    _Float16* wf = (_Float16*)d_ws;   // 2*8*4*64*8 fp16 = 64KB

    pack_w<<<16, 256, 0, stream>>>(w, wf);
    // b fastest in linear block id -> t-adjacent blocks (delta id = 64 == 0 mod 8)
    // land on the same XCD, sharing the 64B x/out lines in that XCD's L2.
    gcn_mfma<<<dim3(B_, T_ / GT), 256, 0, stream>>>(x, dist, wf, bias, gam, bet, out);
}

// Round 5
// 346.646 us; speedup vs baseline: 1.3051x; 1.3051x over previous
//
#include <hip/hip_runtime.h>
#include <math.h>

#define B_ 64
#define P_ 25
#define D_ 128
#define T_ 120
#define L_ 2
#define K_ 4
#define GT 4                  // t-slices per block (1 per wave -> 4 waves/block)
#define LN_EPS 1e-5f
#define HSTRF 132             // fp32 LDS row stride: 16B-aligned, %32==4 -> <=2-way banks

typedef __attribute__((ext_vector_type(8))) _Float16 half8;  // MFMA A/B frag
typedef __attribute__((ext_vector_type(4))) float f4v;       // MFMA accumulator

// Pre-swizzle W[l][k][n] (fp32) into per-lane fp16 B-fragments:
// wf[(((l*8+nt)*4+ks)*64+lane)*8 + j] = f16( W[l][ks*32+(lane>>4)*8+j][nt*16+(lane&15)] )
__global__ __launch_bounds__(256) void pack_w(const float* __restrict__ W,
                                              _Float16* __restrict__ wf) {
    int id = blockIdx.x * 256 + threadIdx.x;          // 0..4095
    int lane = id & 63, rest = id >> 6;
    int ks = rest & 3, nt = (rest >> 2) & 7, l = rest >> 5;
    int n  = nt * 16 + (lane & 15);
    int kb = ks * 32 + (lane >> 4) * 8;
    _Float16 v[8];
    for (int j = 0; j < 8; ++j)
        v[j] = (_Float16)W[((size_t)l * D_ + kb + j) * D_ + n];
    *reinterpret_cast<half8*>(wf + (size_t)id * 8) = *reinterpret_cast<half8*>(v);
}

// Allocator rule (measured R0-R4): __launch_bounds__(256,N) -> VGPR cap ~512/(2N):
// (256,3)->84 [R2/R3], (256,6)->40+spills [R4], plain->104 [R0].
// R3's bfr[8] batching needs ~125 live regs -> was spilled at 84 (that, not the
// idea, caused R3's +100MB WRITE / 237us). This round: (256,2) -> cap ~128.
// LDS (53KB -> 3 blocks/CU = 12 waves) still binds occupancy, so the extra
// registers are free. Structure otherwise identical to R3 (passed, absmax .0625):
// wave w owns t-slice w, no main-loop barriers, 8 wf B-frags batched into regs
// ahead of the mix (L2 latency hidden under ~350cy of ds_read+VALU mix work).
__global__ __launch_bounds__(256, 2) void gcn_mfma(
    const float* __restrict__ x,       // [B,P,D,T]
    const float* __restrict__ dist,    // [B,T,P,P]
    const _Float16* __restrict__ wf,   // packed fp16 W fragments
    const float* __restrict__ biases,  // [L,D]
    const float* __restrict__ gamma,   // [L,D]
    const float* __restrict__ beta,    // [L,D]
    float* __restrict__ out)           // [B,P,D,T]
{
    const int b = blockIdx.x, tg = blockIdx.y;
    const int t0 = tg * GT;
    const int tid = threadIdx.x;
    const int wave = tid >> 6, lane = tid & 63;

    __shared__ __align__(16) float h_lds[GT][P_][HSTRF];  // fp32 h (52.8 KB)
    __shared__ unsigned nbr32[GT][32];                    // packed 4x u8 nbr idx

    // ---- kNN: wave w handles t-slice w, one row per lane (lane<25).
    //      dist loads issued first; selection deferred below the x-load so
    //      HBM latency hides under staging. dr[] register-resident (literal
    //      indices only -> no scratch).
    float dr[P_];
    const bool doknn = (lane < P_);
    if (doknn) {
        const float* drow = dist + (((size_t)b * T_ + t0 + wave) * P_ + lane) * P_;
        #pragma unroll
        for (int q = 0; q < P_; ++q) {
            float v = drow[q];
            dr[q] = (q == lane) ? 1e30f : v;   // mask self, literal index
        }
    }

    // ---- load x -> h fp32 (float4 across the 4 t's: 16B-dense) ----
    {
        const float* xb = x + (size_t)b * P_ * D_ * T_ + t0;
        for (int i = tid; i < P_ * D_; i += 256) {
            int p = i >> 7, d = i & 127;
            float4 v = *reinterpret_cast<const float4*>(xb + (size_t)i * T_);
            h_lds[0][p][d] = v.x;
            h_lds[1][p][d] = v.y;
            h_lds[2][p][d] = v.z;
            h_lds[3][p][d] = v.w;
        }
    }

    // ---- kNN selection (row degree always K+1=5 -> adj = A/5) ----
    if (doknn) {
        unsigned chosen = 0, packed = 0;
        #pragma unroll
        for (int j = 0; j < K_; ++j) {
            float best = 1e29f; int bi = 0;
            #pragma unroll
            for (int q = 0; q < P_; ++q)   // strict < -> lowest index wins ties
                if (!((chosen >> q) & 1u) && dr[q] < best) { best = dr[q]; bi = q; }
            chosen |= 1u << bi;
            packed |= (unsigned)bi << (8 * j);
        }
        nbr32[wave][lane] = packed;
    }
    __syncthreads();   // h + nbr visible (x-load wrote all planes)

    const int t = wave;
    const int m = lane & 15, quad = lane >> 4;
    const int mB = m + 16;
    const bool vB = (mB < P_);
    const int  prB = vB ? mB : 0;
    const float scB = vB ? 0.2f : 0.0f;   // zero out padded rows 25..31
    const float* hb = &h_lds[t][0][0];
    const unsigned nw0 = nbr32[t][m], nw1 = nbr32[t][prB];
    const int n00 = nw0 & 255, n01 = (nw0 >> 8) & 255, n02 = (nw0 >> 16) & 255, n03 = nw0 >> 24;
    const int n10 = nw1 & 255, n11 = (nw1 >> 8) & 255, n12 = (nw1 >> 16) & 255, n13 = nw1 >> 24;

    for (int l = 0; l < L_; ++l) {
        f4v acc[8][2];
        #pragma unroll
        for (int nt = 0; nt < 8; ++nt) {
            acc[nt][0] = (f4v){0.f, 0.f, 0.f, 0.f};
            acc[nt][1] = (f4v){0.f, 0.f, 0.f, 0.f};
        }
        const _Float16* wfl = wf + (size_t)l * 8 * 4 * 64 * 8;

        #pragma unroll
        for (int ks = 0; ks < 4; ++ks) {
            const int ko = ks * 32 + quad * 8;
            const float* base = hb + ko;
            const _Float16* wfk = wfl + (size_t)(ks * 64 + lane) * 8;
            half8 bfr[8];

            // ---- prefetch B-frags nt=0..3 (L2) under tile-0 mix ----
            #pragma unroll
            for (int nt = 0; nt < 4; ++nt)
                bfr[nt] = *reinterpret_cast<const half8*>(wfk + (size_t)nt * 2048);

            // ---- tile 0 mix: 10 float4 ds_reads issued back-to-back ----
            float g0[8];
            {
                const float4* r0 = reinterpret_cast<const float4*>(base + m   * HSTRF);
                const float4* r1 = reinterpret_cast<const float4*>(base + n00 * HSTRF);
                const float4* r2 = reinterpret_cast<const float4*>(base + n01 * HSTRF);
                const float4* r3 = reinterpret_cast<const float4*>(base + n02 * HSTRF);
                const float4* r4 = reinterpret_cast<const float4*>(base + n03 * HSTRF);
                float4 a0 = r0[0], b0 = r0[1];
                float4 a1 = r1[0], b1 = r1[1];
                float4 a2 = r2[0], b2 = r2[1];
                float4 a3 = r3[0], b3 = r3[1];
                float4 a4 = r4[0], b4 = r4[1];
                g0[0] = 0.2f * (a0.x + a1.x + a2.x + a3.x + a4.x);
                g0[1] = 0.2f * (a0.y + a1.y + a2.y + a3.y + a4.y);
                g0[2] = 0.2f * (a0.z + a1.z + a2.z + a3.z + a4.z);
                g0[3] = 0.2f * (a0.w + a1.w + a2.w + a3.w + a4.w);
                g0[4] = 0.2f * (b0.x + b1.x + b2.x + b3.x + b4.x);
                g0[5] = 0.2f * (b0.y + b1.y + b2.y + b3.y + b4.y);
                g0[6] = 0.2f * (b0.z + b1.z + b2.z + b3.z + b4.z);
                g0[7] = 0.2f * (b0.w + b1.w + b2.w + b3.w + b4.w);
            }
            half8 ahi0, alo0;
            #pragma unroll
            for (int j = 0; j < 8; ++j) {
                _Float16 h0 = (_Float16)g0[j];
                ahi0[j] = h0; alo0[j] = (_Float16)(g0[j] - (float)h0);
            }

            // ---- prefetch B-frags nt=4..7 under tile-1 mix ----
            #pragma unroll
            for (int nt = 4; nt < 8; ++nt)
                bfr[nt] = *reinterpret_cast<const half8*>(wfk + (size_t)nt * 2048);

            // ---- tile 1 mix ----
            float g1[8];
            {
                const float4* r0 = reinterpret_cast<const float4*>(base + prB * HSTRF);
                const float4* r1 = reinterpret_cast<const float4*>(base + n10 * HSTRF);
                const float4* r2 = reinterpret_cast<const float4*>(base + n11 * HSTRF);
                const float4* r3 = reinterpret_cast<const float4*>(base + n12 * HSTRF);
                const float4* r4 = reinterpret_cast<const float4*>(base + n13 * HSTRF);
                float4 a0 = r0[0], b0 = r0[1];
                float4 a1 = r1[0], b1 = r1[1];
                float4 a2 = r2[0], b2 = r2[1];
                float4 a3 = r3[0], b3 = r3[1];
                float4 a4 = r4[0], b4 = r4[1];
                g1[0] = scB * (a0.x + a1.x + a2.x + a3.x + a4.x);
                g1[1] = scB * (a0.y + a1.y + a2.y + a3.y + a4.y);
                g1[2] = scB * (a0.z + a1.z + a2.z + a3.z + a4.z);
                g1[3] = scB * (a0.w + a1.w + a2.w + a3.w + a4.w);
                g1[4] = scB * (b0.x + b1.x + b2.x + b3.x + b4.x);
                g1[5] = scB * (b0.y + b1.y + b2.y + b3.y + b4.y);
                g1[6] = scB * (b0.z + b1.z + b2.z + b3.z + b4.z);
                g1[7] = scB * (b0.w + b1.w + b2.w + b3.w + b4.w);
            }
            half8 ahi1, alo1;
            #pragma unroll
            for (int j = 0; j < 8; ++j) {
                _Float16 h1 = (_Float16)g1[j];
                ahi1[j] = h1; alo1[j] = (_Float16)(g1[j] - (float)h1);
            }

            // ---- MFMA burst: all B-frags already resident ----
            #pragma unroll
            for (int nt = 0; nt < 8; ++nt) {
                acc[nt][0] = __builtin_amdgcn_mfma_f32_16x16x32_f16(ahi0, bfr[nt], acc[nt][0], 0, 0, 0);
                acc[nt][0] = __builtin_amdgcn_mfma_f32_16x16x32_f16(alo0, bfr[nt], acc[nt][0], 0, 0, 0);
                acc[nt][1] = __builtin_amdgcn_mfma_f32_16x16x32_f16(ahi1, bfr[nt], acc[nt][1], 0, 0, 0);
                acc[nt][1] = __builtin_amdgcn_mfma_f32_16x16x32_f16(alo1, bfr[nt], acc[nt][1], 0, 0, 0);
            }
        }

        // ---- epilogue in registers: bias + relu + LN + residual into h ----
        // Wave-private h plane: NO barrier needed (same-wave lgkmcnt ordering).
        float bsv[8], gmv[8], btv[8];
        #pragma unroll
        for (int nt = 0; nt < 8; ++nt) {
            int c = l * D_ + nt * 16 + m;
            bsv[nt] = biases[c]; gmv[nt] = gamma[c]; btv[nt] = beta[c];
        }
        // C layout: col = nt*16 + (lane&15), row = mt*16 + quad*4 + r.
        // A row's 128 cols live in the 16 lanes of one quad -> xor 1,2,4,8.
        #pragma unroll
        for (int mt = 0; mt < 2; ++mt) {
            #pragma unroll
            for (int r = 0; r < 4; ++r) {
                const int mm = mt * 16 + quad * 4 + r;
                float z[8], s = 0.f, s2 = 0.f;
                #pragma unroll
                for (int nt = 0; nt < 8; ++nt) {
                    float zz = fmaxf(acc[nt][mt][r] + bsv[nt], 0.f);
                    z[nt] = zz; s += zz; s2 += zz * zz;
                }
                #pragma unroll
                for (int o = 1; o < 16; o <<= 1) {   // reduce within quad (16 lanes)
                    s  += __shfl_xor(s, o);
                    s2 += __shfl_xor(s2, o);
                }
                if (mm < P_) {
                    float mu  = s * (1.f / 128.f);
                    float var = s2 * (1.f / 128.f) - mu * mu;
                    float rs  = rsqrtf(var + LN_EPS);
                    #pragma unroll
                    for (int nt = 0; nt < 8; ++nt)
                        h_lds[t][mm][nt * 16 + m] += (z[nt] - mu) * rs * gmv[nt] + btv[nt];
                }
            }
        }
        // no __syncthreads(): next layer's mix reads only this wave's plane
    }

    __syncthreads();   // store reads all 4 planes cooperatively

    // ---- store: out[b,p,d,t0..t0+3] as float4 ----
    {
        float* ob = out + (size_t)b * P_ * D_ * T_ + t0;
        for (int i = tid; i < P_ * D_; i += 256) {
            int p = i >> 7, d = i & 127;
            float4 v;
            v.x = h_lds[0][p][d];
            v.y = h_lds[1][p][d];
            v.z = h_lds[2][p][d];
            v.w = h_lds[3][p][d];
            *reinterpret_cast<float4*>(ob + (size_t)i * T_) = v;
        }
    }
}

extern "C" void kernel_launch(void* const* d_in, const int* in_sizes, int n_in,
                              void* d_out, int out_size, void* d_ws, size_t ws_size,
                              hipStream_t stream) {
    const float* x    = (const float*)d_in[0];
    const float* dist = (const float*)d_in[1];
    const float* w    = (const float*)d_in[2];
    const float* bias = (const float*)d_in[3];
    const float* gam  = (const float*)d_in[4];
    const float* bet  = (const float*)d_in[5];
    float* out = (float*)d_out;
    _Float16* wf = (_Float16*)d_ws;   // 2*8*4*64*8 fp16 = 64KB

    pack_w<<<16, 256, 0, stream>>>(w, wf);
    // b fastest in linear block id -> t-adjacent blocks (delta id = 64 == 0 mod 8)
    // land on the same XCD, sharing the 64B x/out lines in that XCD's L2.
    gcn_mfma<<<dim3(B_, T_ / GT), 256, 0, stream>>>(x, dist, wf, bias, gam, bet, out);
}